// Round 5
// baseline (958.475 us; speedup 1.0000x reference)
//
#include <hip/hip_runtime.h>
#include <hip/hip_bf16.h>
#include <math.h>

#define Nn 20000
#define Ee 320000
#define Dd 512
#define Hh 4
#define Cc 256
#define Ll 4
#define Bb 16
#define HC 1024               // H*C
#define ETOT (Ee + Nn)        // edges + self loops = 340000
#define NEG_SLOPE 0.2f
#define LN_EPS 1e-5f
#define NBLK ((Nn + 255) / 256)   // 79 scan blocks

typedef __attribute__((ext_vector_type(8))) __bf16 bf16x8;
typedef __attribute__((ext_vector_type(4))) __bf16 bf16x4;
typedef __attribute__((ext_vector_type(4))) float f32x4;

// ---------------- CSR build ----------------

__device__ __forceinline__ void decode_edge(const int* ei, int e, int& s, int& d) {
    if (e < Ee) { s = ei[e]; d = ei[Ee + e]; }
    else        { s = e - Ee; d = e - Ee; }   // self loop
}

__global__ void count_deg_kernel(const int* __restrict__ ei, int* __restrict__ deg) {
    int e = blockIdx.x * blockDim.x + threadIdx.x;
    if (e >= ETOT) return;
    int s, d; decode_edge(ei, e, s, d);
    atomicAdd(&deg[d], 1);
}

__global__ void scan1_kernel(const int* __restrict__ deg, int* __restrict__ tmp,
                             int* __restrict__ bsum) {
    __shared__ int sd[256];
    int tid = threadIdx.x;
    int i = blockIdx.x * 256 + tid;
    sd[tid] = (i < Nn) ? deg[i] : 0;
    __syncthreads();
    for (int off = 1; off < 256; off <<= 1) {
        int t = (tid >= off) ? sd[tid - off] : 0;
        __syncthreads();
        sd[tid] += t;
        __syncthreads();
    }
    if (i < Nn) tmp[i] = sd[tid];
    if (tid == 255) bsum[blockIdx.x] = sd[255];
}

__global__ void scan2_kernel(int* __restrict__ bsum) {   // single block, NBLK<=256
    __shared__ int sd[256];
    int tid = threadIdx.x;
    sd[tid] = (tid < NBLK) ? bsum[tid] : 0;
    __syncthreads();
    for (int off = 1; off < 256; off <<= 1) {
        int t = (tid >= off) ? sd[tid - off] : 0;
        __syncthreads();
        sd[tid] += t;
        __syncthreads();
    }
    if (tid < NBLK) bsum[tid] = sd[tid];
}

__global__ void scan3_kernel(const int* __restrict__ tmp, const int* __restrict__ bsum,
                             const int* __restrict__ deg,
                             int* __restrict__ row_ptr, int* __restrict__ cursor) {
    int i = blockIdx.x * 256 + threadIdx.x;
    if (i >= Nn) return;
    int boff = (blockIdx.x == 0) ? 0 : bsum[blockIdx.x - 1];
    int incl = tmp[i] + boff;
    row_ptr[i + 1] = incl;
    cursor[i] = incl - deg[i];
    if (i == 0) row_ptr[0] = 0;
}

__global__ void scatter_kernel(const int* __restrict__ ei, int* __restrict__ cursor,
                               int* __restrict__ csr_src) {
    int e = blockIdx.x * blockDim.x + threadIdx.x;
    if (e >= ETOT) return;
    int s, d; decode_edge(ei, e, s, d);
    int pos = atomicAdd(&cursor[d], 1);
    csr_src[pos] = s;
}

// ---------------- casts ----------------

__global__ void cast_kernel(const float* __restrict__ in, __bf16* __restrict__ out, int n4) {
    int i = blockIdx.x * blockDim.x + threadIdx.x;
    if (i >= n4) return;
    f32x4 v = ((const f32x4*)in)[i];
    bf16x4 o;
    #pragma unroll
    for (int k = 0; k < 4; ++k) o[k] = (__bf16)v[k];
    ((bf16x4*)out)[i] = o;
}

// W[K][N] fp32 -> WT[N][K] bf16
__global__ void transpose_cast_kernel(const float* __restrict__ W, __bf16* __restrict__ WT,
                                      int K, int N) {
    __shared__ float tile[32][33];
    int n0 = blockIdx.x * 32, k0 = blockIdx.y * 32;
    for (int i = threadIdx.y; i < 32; i += 8)
        tile[i][threadIdx.x] = W[(size_t)(k0 + i) * N + n0 + threadIdx.x];
    __syncthreads();
    for (int i = threadIdx.y; i < 32; i += 8)
        WT[(size_t)(n0 + i) * K + k0 + threadIdx.x] = (__bf16)tile[threadIdx.x][i];
}

// ---------------- MFMA GEMM + fused attention-logit epilogue ----------------
// C[M,1024](bf16) = A[M,K](bf16) @ BT[1024,K]^T, BK=64 (two 32-panels per barrier).
// XCD swizzle: all 8 col-blocks of a row-group land on one XCD (shared L2 copy of A).

__device__ __forceinline__ void async16(const __bf16* g, __bf16* l) {
    __builtin_amdgcn_global_load_lds((const __attribute__((address_space(1))) void*)g,
                                     (__attribute__((address_space(3))) void*)l,
                                     16, 0, 0);
}

__global__ __launch_bounds__(256) void mfma_gemm_kernel(
    const __bf16* __restrict__ A,   // [M][K]
    const __bf16* __restrict__ BT,  // [1024][K]
    __bf16* __restrict__ C,         // [M][1024]
    const float* __restrict__ att_s,  // [4][256] this layer
    const float* __restrict__ att_d,  // [4][256]
    float* __restrict__ asrc,       // [M][4], pre-zeroed
    float* __restrict__ adst,       // [M][4], pre-zeroed
    int M, int K)
{
    // XCD-aware decode: lin%8 = row-block%8 -> same XCD serves all col-blocks of a row
    int lin = blockIdx.y * 8 + blockIdx.x;          // grid (8, 160) -> 1280 ids
    int x8 = lin & 7;
    int t = lin >> 3;
    int cblk = t & 7;
    int rblk = (t >> 3) * 8 + x8;
    int rowBase = rblk * 128, colBase = cblk * 128;
    if (rowBase >= M) return;

    __shared__ __bf16 As[2][128 * 32];
    __shared__ __bf16 Bs[2][128 * 32];
    int tid = threadIdx.x;
    int wave = tid >> 6, lane = tid & 63;
    int m16 = lane & 15, quad = lane >> 4;
    int waveRow = (wave >> 1) * 64, waveCol = (wave & 1) * 64;

    f32x4 acc[4][4] = {};

    int srow = wave * 32 + (lane >> 2);          // staging row, +16 for second half
    int gch0 = (lane & 3) ^ ((srow >> 1) & 3);
    int gch1 = (lane & 3) ^ (((srow + 16) >> 1) & 3);
    int gr0 = rowBase + srow;       if (gr0 >= M) gr0 = M - 1;
    int gr1 = rowBase + srow + 16;  if (gr1 >= M) gr1 = M - 1;
    int ldsOff = srow * 32 + (lane & 3) * 8;

    for (int k0 = 0; k0 < K; k0 += 64) {
        #pragma unroll
        for (int p = 0; p < 2; ++p) {
            int kp = k0 + p * 32;
            async16(A + (size_t)gr0 * K + kp + gch0 * 8, &As[p][ldsOff]);
            async16(A + (size_t)gr1 * K + kp + gch1 * 8, &As[p][ldsOff + 16 * 32]);
            async16(BT + (size_t)(colBase + srow) * K + kp + gch0 * 8, &Bs[p][ldsOff]);
            async16(BT + (size_t)(colBase + srow + 16) * K + kp + gch1 * 8, &Bs[p][ldsOff + 16 * 32]);
        }
        __syncthreads();
        #pragma unroll
        for (int p = 0; p < 2; ++p) {
            bf16x8 af[4], bfr[4];
            #pragma unroll
            for (int i = 0; i < 4; ++i) {
                int row = waveRow + i * 16 + m16;
                af[i] = *(const bf16x8*)&As[p][row * 32 + (quad ^ ((row >> 1) & 3)) * 8];
                int col = waveCol + i * 16 + m16;
                bfr[i] = *(const bf16x8*)&Bs[p][col * 32 + (quad ^ ((col >> 1) & 3)) * 8];
            }
            #pragma unroll
            for (int i = 0; i < 4; ++i)
                #pragma unroll
                for (int j = 0; j < 4; ++j)
                    acc[i][j] = __builtin_amdgcn_mfma_f32_16x16x32_bf16(af[i], bfr[j], acc[i][j], 0, 0, 0);
        }
        __syncthreads();
    }

    // att weights for this wave's 64-col span (single head: 64-span never crosses 256)
    int cbase = colBase + waveCol;
    int head = cbase >> 8;
    float as4[4], ad4[4];
    #pragma unroll
    for (int j = 0; j < 4; ++j) {
        int off = (cbase + j * 16 + m16) & 255;
        as4[j] = att_s[head * 256 + off];
        ad4[j] = att_d[head * 256 + off];
    }

    // store C (bf16) + fused alpha partials
    #pragma unroll
    for (int i = 0; i < 4; ++i) {
        int r0 = rowBase + waveRow + i * 16 + quad * 4;
        #pragma unroll
        for (int r = 0; r < 4; ++r) {
            int row = r0 + r;
            float ps = 0.f, pd = 0.f;
            #pragma unroll
            for (int j = 0; j < 4; ++j) {
                float h = acc[i][j][r];
                ps += h * as4[j];
                pd += h * ad4[j];
                if (row < M)
                    C[(size_t)row * HC + colBase + waveCol + j * 16 + m16] = (__bf16)h;
            }
            #pragma unroll
            for (int off = 1; off < 16; off <<= 1) {
                ps += __shfl_xor(ps, off);
                pd += __shfl_xor(pd, off);
            }
            if (m16 == 0 && row < M) {
                atomicAdd(&asrc[row * Hh + head], ps);
                atomicAdd(&adst[row * Hh + head], pd);
            }
        }
    }
}

// ---------------- softmax-weighted aggregation (single pass) ----------------
// one block per node. Unnormalized accumulate + running exp-sum; divide at end.
// Half-block 0 takes even edges, half-block 1 odd edges; 16B bf16x8 gathers.

__global__ __launch_bounds__(256) void agg_kernel(const __bf16* __restrict__ hb,
                                                  const float* __restrict__ asrc,
                                                  const float* __restrict__ adst,
                                                  const int* __restrict__ row_ptr,
                                                  const int* __restrict__ csr_src,
                                                  const float* __restrict__ bias_l,
                                                  __bf16* __restrict__ outb) {
    int n = blockIdx.x;
    int tid = threadIdx.x;
    int wave = tid >> 6, lane = tid & 63;
    int half = tid >> 7;        // 0/1: which edge parity this thread gathers
    int u = tid & 127;          // channel octet: channels [8u, 8u+8)
    int headU = u >> 5;         // head of those channels
    int start = row_ptr[n], end = row_ptr[n + 1];

    __shared__ float adst_sh[4], inv_sh[4];
    __shared__ float wsh[256];      // [edge_in_chunk][head] unnormalized exp
    __shared__ int ssh[64];
    __shared__ float xacc[128][8];  // half-1 partial channel sums

    if (tid < 4) adst_sh[tid] = adst[n * Hh + tid];
    __syncthreads();

    float acc[8] = {};
    float dsum = 0.f;               // per-lane partial of denom (head = wave)

    for (int base = start; base < end; base += 64) {
        int cnt = min(64, end - base);
        int eidx = tid >> 2, hh = tid & 3;
        if (eidx < cnt) {
            int s = csr_src[base + eidx];
            if (hh == 0) ssh[eidx] = s;
            float z = asrc[s * Hh + hh] + adst_sh[hh];
            z = (z > 0.f) ? z : NEG_SLOPE * z;
            wsh[eidx * 4 + hh] = __expf(z);
        }
        __syncthreads();
        if (lane < cnt) dsum += wsh[lane * 4 + wave];
        int e = 0;
        for (; e + 4 <= cnt; e += 4) {
            int i0 = e + half, i1 = e + 2 + half;
            bf16x8 v0 = ((const bf16x8*)(hb + (size_t)ssh[i0] * HC))[u];
            bf16x8 v1 = ((const bf16x8*)(hb + (size_t)ssh[i1] * HC))[u];
            float w0 = wsh[i0 * 4 + headU], w1 = wsh[i1 * 4 + headU];
            #pragma unroll
            for (int k = 0; k < 8; ++k) {
                acc[k] += w0 * (float)v0[k];
                acc[k] += w1 * (float)v1[k];
            }
        }
        for (; e < cnt; e += 2) {
            int i0 = e + half;
            if (i0 < cnt) {
                bf16x8 v0 = ((const bf16x8*)(hb + (size_t)ssh[i0] * HC))[u];
                float w0 = wsh[i0 * 4 + headU];
                #pragma unroll
                for (int k = 0; k < 8; ++k) acc[k] += w0 * (float)v0[k];
            }
        }
        __syncthreads();
    }

    // denom: reduce dsum within each wave (wave w holds head w)
    #pragma unroll
    for (int off = 32; off > 0; off >>= 1) dsum += __shfl_down(dsum, off);
    if (lane == 0) inv_sh[wave] = 1.f / (dsum + 1e-16f);

    if (half == 1) {
        #pragma unroll
        for (int k = 0; k < 8; ++k) xacc[u][k] = acc[k];
    }
    __syncthreads();
    if (half == 0) {
        float inv = inv_sh[headU];
        f32x4 b0 = ((const f32x4*)bias_l)[u * 2];
        f32x4 b1 = ((const f32x4*)bias_l)[u * 2 + 1];
        bf16x8 o;
        #pragma unroll
        for (int k = 0; k < 8; ++k) {
            float bv = (k < 4) ? b0[k] : b1[k - 4];
            float v = (acc[k] + xacc[u][k]) * inv + bv;
            o[k] = (__bf16)fmaxf(v, 0.f);   // bias + relu
        }
        ((bf16x8*)(outb + (size_t)n * HC))[u] = o;
    }
}

// ---------------- global mean pool (batch sorted -> contiguous ranges) ----------------

__device__ __forceinline__ int lower_bound_batch(const int* __restrict__ batch, int val) {
    int lo = 0, hi = Nn;
    while (lo < hi) { int mid = (lo + hi) >> 1; if (batch[mid] < val) lo = mid + 1; else hi = mid; }
    return lo;
}

__global__ void pool_kernel(const __bf16* __restrict__ h2b, const int* __restrict__ batch,
                            float* __restrict__ pooled) {
    int b = blockIdx.x, part = blockIdx.y;   // grid (B, 8)
    int tid = threadIdx.x;
    int start = lower_bound_batch(batch, b);
    int end   = lower_bound_batch(batch, b + 1);
    int len = end - start;
    int chunk = (len + 7) / 8;
    int s0 = start + part * chunk;
    int s1 = min(s0 + chunk, end);
    float acc[4] = {0.f, 0.f, 0.f, 0.f};
    for (int n = s0; n < s1; ++n) {
        bf16x4 v = ((const bf16x4*)(h2b + (size_t)n * HC))[tid];
        #pragma unroll
        for (int k = 0; k < 4; ++k) acc[k] += (float)v[k];
    }
    #pragma unroll
    for (int k = 0; k < 4; ++k)
        atomicAdd(&pooled[b * HC + tid * 4 + k], acc[k]);
}

// ---------------- projection (k-split) + layernorm ----------------

__global__ __launch_bounds__(512) void proj_partial_kernel(const float* __restrict__ pooled,
                                                           const int* __restrict__ batch,
                                                           const float* __restrict__ projW,
                                                           float* __restrict__ projOut) {
    int b = blockIdx.x, part = blockIdx.y;   // grid (16, 8)
    int d = threadIdx.x;                     // 512
    int start = lower_bound_batch(batch, b);
    int end   = lower_bound_batch(batch, b + 1);
    float inv = 1.0f / fmaxf((float)(end - start), 1.0f);
    float acc = 0.f;
    int k0 = part * 128;
    for (int k = k0; k < k0 + 128; ++k)
        acc += pooled[b * HC + k] * projW[(size_t)k * Dd + d];
    atomicAdd(&projOut[b * Dd + d], acc * inv);
}

__global__ __launch_bounds__(512) void ln_kernel(const float* __restrict__ projOut,
                                                 const float* __restrict__ projb,
                                                 const float* __restrict__ gamma,
                                                 const float* __restrict__ beta,
                                                 float* __restrict__ out) {
    int b = blockIdx.x;
    int d = threadIdx.x;
    __shared__ float red[512];
    float o = projOut[b * Dd + d] + projb[d];
    red[d] = o;
    __syncthreads();
    for (int off = 256; off > 0; off >>= 1) {
        if (d < off) red[d] += red[d + off];
        __syncthreads();
    }
    float mu = red[0] / (float)Dd;
    __syncthreads();
    float df = o - mu;
    red[d] = df * df;
    __syncthreads();
    for (int off = 256; off > 0; off >>= 1) {
        if (d < off) red[d] += red[d + off];
        __syncthreads();
    }
    float var = red[0] / (float)Dd;
    out[b * Dd + d] = df / sqrtf(var + LN_EPS) * gamma[d] + beta[d];
}

// ---------------- launch ----------------

extern "C" void kernel_launch(void* const* d_in, const int* in_sizes, int n_in,
                              void* d_out, int out_size, void* d_ws, size_t ws_size,
                              hipStream_t stream) {
    const float* x         = (const float*)d_in[0];
    const int*   ei        = (const int*)d_in[1];
    const int*   batch     = (const int*)d_in[2];
    const float* W0        = (const float*)d_in[3];
    const float* W_rest    = (const float*)d_in[4];
    const float* att_src   = (const float*)d_in[5];
    const float* att_dst   = (const float*)d_in[6];
    const float* conv_bias = (const float*)d_in[7];
    const float* proj_W    = (const float*)d_in[8];
    const float* proj_b    = (const float*)d_in[9];
    const float* ln_gamma  = (const float*)d_in[10];
    const float* ln_beta   = (const float*)d_in[11];
    float* out = (float*)d_out;

    char* ws = (char*)d_ws;
    size_t off = 0;
    auto alloc = [&](size_t bytes) {
        void* p = ws + off;
        off = (off + bytes + 255) & ~(size_t)255;
        return p;
    };
    __bf16* h1b     = (__bf16*)alloc((size_t)Nn * HC * 2);   // GEMM out (bf16)
    __bf16* h2b     = (__bf16*)alloc((size_t)Nn * HC * 2);   // layer out (bf16)
    __bf16* xb      = (__bf16*)alloc((size_t)Nn * Dd * 2);
    __bf16* W0T     = (__bf16*)alloc((size_t)HC * Dd * 2);
    __bf16* WrT     = (__bf16*)alloc((size_t)3 * HC * HC * 2);
    float*  asrc    = (float*)alloc((size_t)Nn * Hh * 4);    // contiguous with adst
    float*  adst    = (float*)alloc((size_t)Nn * Hh * 4);
    int*    deg     = (int*)alloc((size_t)Nn * 4);
    int*    tmp     = (int*)alloc((size_t)Nn * 4);
    int*    bsum    = (int*)alloc((size_t)256 * 4);
    int*    row_ptr = (int*)alloc((size_t)(Nn + 1) * 4);
    int*    cursor  = (int*)alloc((size_t)Nn * 4);
    int*    csr_src = (int*)alloc((size_t)ETOT * 4);
    float*  pooled  = (float*)alloc((size_t)Bb * HC * 4);
    float*  projOut = (float*)alloc((size_t)Bb * Dd * 4);
    (void)ws_size; (void)in_sizes; (void)n_in; (void)out_size;

    // ---- build CSR by destination ----
    hipMemsetAsync(deg, 0, (size_t)Nn * 4, stream);
    count_deg_kernel<<<(ETOT + 255) / 256, 256, 0, stream>>>(ei, deg);
    scan1_kernel<<<NBLK, 256, 0, stream>>>(deg, tmp, bsum);
    scan2_kernel<<<1, 256, 0, stream>>>(bsum);
    scan3_kernel<<<NBLK, 256, 0, stream>>>(tmp, bsum, deg, row_ptr, cursor);
    scatter_kernel<<<(ETOT + 255) / 256, 256, 0, stream>>>(ei, cursor, csr_src);

    // ---- bf16 casts / weight transposes ----
    cast_kernel<<<(Nn * Dd / 4 + 255) / 256, 256, 0, stream>>>(x, xb, Nn * Dd / 4);
    transpose_cast_kernel<<<dim3(HC / 32, Dd / 32), dim3(32, 8), 0, stream>>>(W0, W0T, Dd, HC);
    for (int l = 0; l < 3; ++l)
        transpose_cast_kernel<<<dim3(HC / 32, HC / 32), dim3(32, 8), 0, stream>>>(
            W_rest + (size_t)l * HC * HC, WrT + (size_t)l * HC * HC, HC, HC);

    // ---- GAT layers ----
    dim3 gemm_grid(8, 160);   // 1280 swizzled ids -> (157 row-blocks, 8 col-blocks)
    for (int l = 0; l < Ll; ++l) {
        const __bf16* Afeat = (l == 0) ? xb : h2b;
        int K = (l == 0) ? Dd : HC;
        const __bf16* BT = (l == 0) ? W0T : (WrT + (size_t)(l - 1) * HC * HC);
        hipMemsetAsync(asrc, 0, (size_t)Nn * Hh * 4 * 2, stream);   // asrc+adst contiguous
        mfma_gemm_kernel<<<gemm_grid, 256, 0, stream>>>(
            Afeat, BT, h1b, att_src + l * HC, att_dst + l * HC, asrc, adst, Nn, K);
        agg_kernel<<<Nn, 256, 0, stream>>>(h1b, asrc, adst, row_ptr, csr_src,
                                           conv_bias + l * HC, h2b);
    }

    // ---- pool + proj + layernorm ----
    hipMemsetAsync(pooled, 0, (size_t)Bb * HC * 4, stream);
    hipMemsetAsync(projOut, 0, (size_t)Bb * Dd * 4, stream);
    pool_kernel<<<dim3(Bb, 8), 256, 0, stream>>>(h2b, batch, pooled);
    proj_partial_kernel<<<dim3(Bb, 8), 512, 0, stream>>>(pooled, batch, proj_W, projOut);
    ln_kernel<<<Bb, 512, 0, stream>>>(projOut, proj_b, ln_gamma, ln_beta, out);
}